// Round 7
// baseline (342.018 us; speedup 1.0000x reference)
//
#include <hip/hip_runtime.h>
#include <hip/hip_bf16.h>

#define GRID14 14
#define SS 196
#define EE 768
#define HH 4
#define HD 192
#define BB 64
#define MM (BB*SS)       // 12544
#define SE (SS*EE)       // 150528

typedef __bf16 bf16x8 __attribute__((ext_vector_type(8)));
typedef __bf16 bf16x4 __attribute__((ext_vector_type(4)));
typedef float floatx4 __attribute__((ext_vector_type(4)));

__device__ __forceinline__ void glds16(const void* g, void* l) {
  __builtin_amdgcn_global_load_lds(
      (const __attribute__((address_space(1))) unsigned int*)g,
      (__attribute__((address_space(3))) unsigned int*)l, 16, 0, 0);
}

__device__ __forceinline__ unsigned short bfbits(float f) {
  __hip_bfloat16 h = __float2bfloat16(f);
  return *(unsigned short*)&h;
}

// ---------------- patch extraction: x[64,3,224,224] f32 -> patches[12544,768] bf16
// 8 elems/thread: 2x float4 reads (16B-aligned), one 16B write.
__global__ __launch_bounds__(256) void patch_kernel(const float* __restrict__ x,
                                                    __hip_bfloat16* __restrict__ p) {
  int idx = blockIdx.x * 256 + threadIdx.x;   // 8-elem group, total MM*96
  int k8 = idx % 96;
  int m  = idx / 96;
  int b = m / SS, s = m - b*SS;
  int gy = s / GRID14, gx = s - gy*GRID14;
  int k = k8 * 8;
  int c = k >> 8, py = (k >> 4) & 15, px = k & 15;
  const float* src = x + ((size_t)(b*3 + c)*224 + gy*16 + py)*224 + gx*16 + px;
  float4 f0 = *(const float4*)src;
  float4 f1 = *(const float4*)(src + 4);
  union { uint4 q; unsigned short u[8]; } t;
  t.u[0] = bfbits(f0.x); t.u[1] = bfbits(f0.y);
  t.u[2] = bfbits(f0.z); t.u[3] = bfbits(f0.w);
  t.u[4] = bfbits(f1.x); t.u[5] = bfbits(f1.y);
  t.u[6] = bfbits(f1.z); t.u[7] = bfbits(f1.w);
  *(uint4*)(p + (size_t)idx * 8) = t.q;
}

// ---------------- weight conversion + QKV weight/bias concat + stats zeroing
__global__ __launch_bounds__(256) void convert_weights(
    const float* __restrict__ cw, const float* __restrict__ wq,
    const float* __restrict__ wk, const float* __restrict__ wv,
    const float* __restrict__ wo, const float* __restrict__ bq,
    const float* __restrict__ bk, const float* __restrict__ bv,
    __hip_bfloat16* __restrict__ cw_b, __hip_bfloat16* __restrict__ qkvw_b,
    __hip_bfloat16* __restrict__ wo_b, float* __restrict__ qkv_bias,
    float* __restrict__ stats) {
  int i = blockIdx.x * 256 + threadIdx.x;
  const int WN = EE * EE;
  if (i < WN) {
    cw_b[i] = __float2bfloat16(cw[i]);
    wo_b[i] = __float2bfloat16(wo[i]);
    qkvw_b[i]        = __float2bfloat16(wq[i]);
    qkvw_b[WN + i]   = __float2bfloat16(wk[i]);
    qkvw_b[2*WN + i] = __float2bfloat16(wv[i]);
  }
  if (i < EE) { qkv_bias[i] = bq[i]; qkv_bias[EE+i] = bk[i]; qkv_bias[2*EE+i] = bv[i]; }
  if (i < 256) stats[i] = 0.f;
}

// ---------------- bf16 MFMA GEMM: out[M,N] = A[M,K] @ W[N,K]^T + bias (+skip)
// 128x128 tile, BK=64, global_load_lds width-16, XOR-swizzled LDS.
// outF path: fp32 direct stores (+ optional bf16 skip). outB path: LDS-staged
// 16B/lane stores. Optional fused LayerNorm stats in either path.
__global__ __launch_bounds__(256, 4) void gemm_bt(
    const __hip_bfloat16* __restrict__ A, const __hip_bfloat16* __restrict__ W,
    const float* __restrict__ bias, const __hip_bfloat16* __restrict__ skipB,
    float* __restrict__ outF, __hip_bfloat16* __restrict__ outB,
    float* __restrict__ stats, int N, int K) {
  __shared__ __align__(16) union SM {
    unsigned short ab[2][128*64];   // As, Bs (main loop)  32 KB
    unsigned short c[128*136];      // epilogue staging    34816 B
  } sm;
  __shared__ float red[16];
  const int tileM = blockIdx.y * 128;
  const int tileN = blockIdx.x * 128;
  const int tid  = threadIdx.x;
  const int lane = tid & 63;
  const int wave = tid >> 6;
  const int wrow = (wave >> 1) * 64;
  const int wcol = (wave & 1) * 64;
  const int lm = lane & 15;
  const int lq = lane >> 4;

  const int rt = tid >> 3;
  const int pc = tid & 7;
  const int sc = pc ^ (rt & 7);
  const __hip_bfloat16* aP = A + (size_t)(tileM + rt) * K + sc * 8;
  const __hip_bfloat16* bP = W + (size_t)(tileN + rt) * K + sc * 8;
  unsigned short* asl = sm.ab[0] + tid * 8;
  unsigned short* bsl = sm.ab[1] + tid * 8;
  const int f0 = lm & 7;

  floatx4 acc[4][4];
  #pragma unroll
  for (int i = 0; i < 4; ++i)
    #pragma unroll
    for (int j = 0; j < 4; ++j) acc[i][j] = (floatx4)0.0f;

  for (int k0 = 0; k0 < K; k0 += 64) {
    __syncthreads();
    #pragma unroll
    for (int i = 0; i < 4; ++i) glds16(aP + k0 + (size_t)(32*i)*K, asl + 2048*i);
    #pragma unroll
    for (int i = 0; i < 4; ++i) glds16(bP + k0 + (size_t)(32*i)*K, bsl + 2048*i);
    __syncthreads();
    #pragma unroll
    for (int h = 0; h < 2; ++h) {
      bf16x8 af[4], bfr[4];
      #pragma unroll
      for (int i = 0; i < 4; ++i)
        af[i]  = *(const bf16x8*)&sm.ab[0][(wrow + i*16 + lm)*64 + (((lq + 4*h) ^ f0))*8];
      #pragma unroll
      for (int j = 0; j < 4; ++j)
        bfr[j] = *(const bf16x8*)&sm.ab[1][(wcol + j*16 + lm)*64 + (((lq + 4*h) ^ f0))*8];
      #pragma unroll
      for (int i = 0; i < 4; ++i)
        #pragma unroll
        for (int j = 0; j < 4; ++j)
          acc[i][j] = __builtin_amdgcn_mfma_f32_16x16x32_bf16(af[i], bfr[j], acc[i][j], 0, 0, 0);
    }
  }

  const int rq = lq * 4;
  const int sA = tileM / SS;
  const int boundary = (sA + 1) * SS;
  float p0s = 0.f, p0q = 0.f, p1s = 0.f, p1q = 0.f;

  if (outF) {
    #pragma unroll
    for (int j = 0; j < 4; ++j) {
      int n = tileN + wcol + j*16 + lm;
      float bj = bias[n];
      #pragma unroll
      for (int i = 0; i < 4; ++i) {
        int mb = tileM + wrow + i*16 + rq;
        #pragma unroll
        for (int r = 0; r < 4; ++r) {
          int row = mb + r;
          size_t o = (size_t)row * N + n;
          float v = acc[i][j][r] + bj;
          if (skipB) v += __bfloat162float(skipB[o]);
          outF[o] = v;
          if (stats) {
            if (row < boundary) { p0s += v; p0q += v*v; }
            else                { p1s += v; p1q += v*v; }
          }
        }
      }
    }
  } else {
    // bf16 output: stage tile in LDS, then 16B/lane coalesced stores
    __syncthreads();
    #pragma unroll
    for (int j = 0; j < 4; ++j) {
      int n = wcol + j*16 + lm;
      float bj = bias[tileN + n];
      #pragma unroll
      for (int i = 0; i < 4; ++i) {
        int rowb = wrow + i*16 + rq;
        #pragma unroll
        for (int r = 0; r < 4; ++r) {
          float v = acc[i][j][r] + bj;
          sm.c[(rowb + r)*136 + n] = bfbits(v);
          if (stats) {
            int row = tileM + rowb + r;
            if (row < boundary) { p0s += v; p0q += v*v; }
            else                { p1s += v; p1q += v*v; }
          }
        }
      }
    }
    __syncthreads();
    #pragma unroll
    for (int f = tid; f < 2048; f += 256) {
      int row = f >> 4, ch = (f & 15) * 8;
      *(uint4*)(outB + (size_t)(tileM + row) * N + tileN + ch) =
          *(const uint4*)&sm.c[row*136 + ch];
    }
  }

  if (stats) {
    #pragma unroll
    for (int off = 32; off; off >>= 1) {
      p0s += __shfl_down(p0s, off); p0q += __shfl_down(p0q, off);
      p1s += __shfl_down(p1s, off); p1q += __shfl_down(p1q, off);
    }
    if (lane == 0) {
      red[wave*4+0] = p0s; red[wave*4+1] = p0q;
      red[wave*4+2] = p1s; red[wave*4+3] = p1q;
    }
    __syncthreads();
    if (tid == 0) {
      atomicAdd(&stats[2*sA],   red[0]+red[4]+red[8]+red[12]);
      atomicAdd(&stats[2*sA+1], red[1]+red[5]+red[9]+red[13]);
      if (boundary <= tileM + 127 && sA + 1 < BB) {
        atomicAdd(&stats[2*sA+2], red[2]+red[6]+red[10]+red[14]);
        atomicAdd(&stats[2*sA+3], red[3]+red[7]+red[11]+red[15]);
      }
    }
  }
}

// ---------------- LN apply (stats = per-sample {sum, sumsq}); input fp32 OR bf16
__global__ __launch_bounds__(256) void ln_apply(const float* __restrict__ inF,
    const __hip_bfloat16* __restrict__ inB, const float* __restrict__ stats,
    const float* __restrict__ w, const float* __restrict__ bias,
    __hip_bfloat16* __restrict__ outB, float* __restrict__ outF) {
  int idx = blockIdx.x * 256 + threadIdx.x;      // float4 index, total 64*SE/4
  int samp = idx / (SE/4);
  int pos  = idx - samp * (SE/4);
  float S1 = stats[samp*2], S2 = stats[samp*2+1];
  float mu = S1 * (1.0f/SE);
  float var = S2 * (1.0f/SE) - mu*mu;
  float rstd = rsqrtf(var + 1e-5f);
  float4 v;
  if (inF) {
    v = ((const float4*)inF)[idx];
  } else {
    ushort4 u = ((const ushort4*)inB)[idx];
    union { unsigned int i; float f; } a, b2, c, d;
    a.i = (unsigned)u.x << 16; b2.i = (unsigned)u.y << 16;
    c.i = (unsigned)u.z << 16; d.i = (unsigned)u.w << 16;
    v.x = a.f; v.y = b2.f; v.z = c.f; v.w = d.f;
  }
  float4 w4 = ((const float4*)w)[pos];
  float4 b4 = ((const float4*)bias)[pos];
  float4 r;
  r.x = (v.x - mu)*rstd*w4.x + b4.x;
  r.y = (v.y - mu)*rstd*w4.y + b4.y;
  r.z = (v.z - mu)*rstd*w4.z + b4.z;
  r.w = (v.w - mu)*rstd*w4.w + b4.w;
  if (outF) {
    ((float4*)outF)[idx] = r;
  } else {
    ushort4 us;
    us.x = bfbits(r.x); us.y = bfbits(r.y);
    us.z = bfbits(r.z); us.w = bfbits(r.w);
    *(ushort4*)(outB + (size_t)idx * 4) = us;
  }
}

// ---------------- MFMA flash attention: one block per (b,h)
__device__ __forceinline__ int kv_byte(int row, int col) {
  int c8 = col >> 3;
  int swz = (c8 & 24) | ((c8 ^ row) & 7);
  return row*384 + swz*16 + (col & 7)*2;
}

__global__ __launch_bounds__(256) void attn_mfma(const __hip_bfloat16* __restrict__ qkv,
                                                 __hip_bfloat16* __restrict__ o) {
  extern __shared__ char smem[];
  unsigned short* Pb = (unsigned short*)(smem + 75264);   // stride 212 elems
  const int bh = blockIdx.x;
  const int b = bh >> 2, h = bh & 3;
  const int tid = threadIdx.x, lane = tid & 63, wave = tid >> 6;
  const int lm = lane & 15, lq = lane >> 4;

  {
    const __hip_bfloat16* kbase = qkv + (size_t)b*SS*2304 + EE + h*HD;
    for (int f = tid; f < 196*24; f += 256) {
      int row = f / 24, c8 = f % 24;
      uint4 v = *(const uint4*)(kbase + (size_t)row*2304 + c8*8);
      int swz = (c8 & 24) | ((c8 ^ row) & 7);
      *(uint4*)(smem + row*384 + swz*16) = v;
    }
  }
  __syncthreads();

  const float scale = 0.07216878364870323f;   // 1/sqrt(192)
  for (int qt = wave; qt < 13; qt += 4) {
    bf16x8 qf[6];
    const __hip_bfloat16* qrow = qkv + (size_t)(b*SS + qt*16 + lm)*2304 + h*HD + lq*8;
    #pragma unroll
    for (int c = 0; c < 6; ++c) qf[c] = *(const bf16x8*)(qrow + c*32);
    floatx4 acc[13];
    #pragma unroll
    for (int nt = 0; nt < 13; ++nt) acc[nt] = (floatx4)0.0f;
    #pragma unroll
    for (int nt = 0; nt < 13; ++nt) {
      int n = nt*16 + lm;
      #pragma unroll
      for (int c = 0; c < 6; ++c) {
        bf16x8 kf = *(const bf16x8*)(smem + kv_byte(n, c*32 + lq*8));
        acc[nt] = __builtin_amdgcn_mfma_f32_16x16x32_bf16(qf[c], kf, acc[nt], 0, 0, 0);
      }
    }
    float rmax[4] = {-1e30f, -1e30f, -1e30f, -1e30f};
    #pragma unroll
    for (int nt = 0; nt < 13; ++nt) {
      bool valid = (nt < 12) | (lm < 4);
      #pragma unroll
      for (int r = 0; r < 4; ++r) {
        float v = acc[nt][r] * scale;
        acc[nt][r] = v;
        if (valid) rmax[r] = fmaxf(rmax[r], v);
      }
    }
    #pragma unroll
    for (int x = 1; x < 16; x <<= 1)
      #pragma unroll
      for (int r = 0; r < 4; ++r) rmax[r] = fmaxf(rmax[r], __shfl_xor(rmax[r], x));
    float rsum[4] = {0.f, 0.f, 0.f, 0.f};
    #pragma unroll
    for (int nt = 0; nt < 13; ++nt) {
      bool valid = (nt < 12) | (lm < 4);
      #pragma unroll
      for (int r = 0; r < 4; ++r) {
        float e = valid ? __expf(acc[nt][r] - rmax[r]) : 0.f;
        acc[nt][r] = e;
        rsum[r] += e;
      }
    }
    #pragma unroll
    for (int x = 1; x < 16; x <<= 1)
      #pragma unroll
      for (int r = 0; r < 4; ++r) rsum[r] += __shfl_xor(rsum[r], x);
    float inv[4];
    #pragma unroll
    for (int r = 0; r < 4; ++r) inv[r] = 1.0f / rsum[r];
    #pragma unroll
    for (int nt = 0; nt < 13; ++nt) {
      int col = nt*16 + lm;
      #pragma unroll
      for (int r = 0; r < 4; ++r) {
        int row = qt*16 + lq*4 + r;
        if (row < SS) {
          Pb[row*212 + col] = bfbits(acc[nt][r] * inv[r]);
        }
      }
    }
  }
  __syncthreads();

  {
    const __hip_bfloat16* vbase = qkv + (size_t)b*SS*2304 + 2*EE + h*HD;
    for (int f = tid; f < 196*24; f += 256) {
      int row = f / 24, c8 = f % 24;
      uint4 v = *(const uint4*)(vbase + (size_t)row*2304 + c8*8);
      int swz = (c8 & 24) | ((c8 ^ row) & 7);
      *(uint4*)(smem + row*384 + swz*16) = v;
    }
  }
  __syncthreads();

  const int d0 = wave * 48;
  union U8 { bf16x8 v; unsigned short u[8]; };
  U8 vf[3][6]; U8 vtail[3];
  #pragma unroll
  for (int nn = 0; nn < 3; ++nn) {
    int d = d0 + nn*16 + lm;
    #pragma unroll
    for (int c = 0; c < 6; ++c) {
      int sb = c*32 + lq*8;
      #pragma unroll
      for (int j = 0; j < 8; ++j)
        vf[nn][c].u[j] = *(const unsigned short*)(smem + kv_byte(sb + j, d));
    }
    #pragma unroll
    for (int j = 0; j < 8; ++j) vtail[nn].u[j] = 0;
    if (lane < 16) {
      #pragma unroll
      for (int j = 0; j < 4; ++j)
        vtail[nn].u[j] = *(const unsigned short*)(smem + kv_byte(192 + j, d0 + nn*16 + lane));
    }
  }

  for (int qt = 0; qt < 13; ++qt) {
    floatx4 O[3];
    #pragma unroll
    for (int nn = 0; nn < 3; ++nn) O[nn] = (floatx4)0.0f;
    #pragma unroll
    for (int c = 0; c < 6; ++c) {
      int e0 = (qt*16 + lm)*212 + c*32 + lq*8;
      bf16x4 lo = *(const bf16x4*)(Pb + e0);
      bf16x4 hi = *(const bf16x4*)(Pb + e0 + 4);
      bf16x8 pf = __builtin_shufflevector(lo, hi, 0, 1, 2, 3, 4, 5, 6, 7);
      #pragma unroll
      for (int nn = 0; nn < 3; ++nn)
        O[nn] = __builtin_amdgcn_mfma_f32_16x16x32_bf16(pf, vf[nn][c].v, O[nn], 0, 0, 0);
    }
    {
      U8 pt;
      #pragma unroll
      for (int j = 0; j < 8; ++j) pt.u[j] = 0;
      if (lane < 16) {
        #pragma unroll
        for (int j = 0; j < 4; ++j) pt.u[j] = Pb[(qt*16 + lane)*212 + 192 + j];
      }
      #pragma unroll
      for (int nn = 0; nn < 3; ++nn)
        O[nn] = __builtin_amdgcn_mfma_f32_16x16x32_bf16(pt.v, vtail[nn].v, O[nn], 0, 0, 0);
    }
    #pragma unroll
    for (int nn = 0; nn < 3; ++nn) {
      #pragma unroll
      for (int r = 0; r < 4; ++r) {
        int q = qt*16 + lq*4 + r;
        if (q < SS)
          o[(size_t)(b*SS + q)*EE + h*HD + d0 + nn*16 + lm] = __float2bfloat16(O[nn][r]);
      }
    }
  }
}

extern "C" void kernel_launch(void* const* d_in, const int* in_sizes, int n_in,
                              void* d_out, int out_size, void* d_ws, size_t ws_size,
                              hipStream_t stream) {
  const float* x      = (const float*)d_in[0];
  const float* conv_w = (const float*)d_in[1];
  const float* conv_b = (const float*)d_in[2];
  const float* wq = (const float*)d_in[3];
  const float* bq = (const float*)d_in[4];
  const float* wk = (const float*)d_in[5];
  const float* bk = (const float*)d_in[6];
  const float* wv = (const float*)d_in[7];
  const float* bv = (const float*)d_in[8];
  const float* wo = (const float*)d_in[9];
  const float* bo = (const float*)d_in[10];
  const float* ln1w = (const float*)d_in[11];
  const float* ln1b = (const float*)d_in[12];
  const float* ln2w = (const float*)d_in[13];
  const float* ln2b = (const float*)d_in[14];
  float* out = (float*)d_out;

  char* ws = (char*)d_ws;
  __hip_bfloat16* patches = (__hip_bfloat16*)(ws);                // 19267584
  __hip_bfloat16* cw_b    = (__hip_bfloat16*)(ws + 19267584);     //  1179648
  __hip_bfloat16* qkvw_b  = (__hip_bfloat16*)(ws + 20447232);     //  3538944
  __hip_bfloat16* wo_b    = (__hip_bfloat16*)(ws + 23986176);     //  1179648
  float*          qkv_b   = (float*)         (ws + 25165824);     //     9216
  __hip_bfloat16* emb_b   = (__hip_bfloat16*)(ws + 25175040);     // 19267584 (bf16 now)
  __hip_bfloat16* hbuf    = (__hip_bfloat16*)(ws + 63710208);     // 19267584
  __hip_bfloat16* qkv     = (__hip_bfloat16*)(ws + 82977792);     // 57802752
  __hip_bfloat16* obuf    = (__hip_bfloat16*)(ws + 140780544);    // 19267584
  float*          stats   = (float*)(ws + 160048128);             //     1024

  // stats[0..127] = LN1 {sum,sumsq} per sample; stats[128..255] = LN2
  convert_weights<<<2304, 256, 0, stream>>>(conv_w, wq, wk, wv, wo, bq, bk, bv,
                                            cw_b, qkvw_b, wo_b, qkv_b, stats);
  patch_kernel<<<MM*96/256, 256, 0, stream>>>(x, patches);
  // emb = patches @ conv_w^T + conv_b (bf16 out) + fused LN1 stats
  gemm_bt<<<dim3(6, 98), 256, 0, stream>>>(patches, cw_b, conv_b, nullptr,
                                           nullptr, emb_b, stats, EE, EE);
  ln_apply<<<BB*SE/4/256, 256, 0, stream>>>(nullptr, emb_b, stats, ln1w, ln1b,
                                            hbuf, nullptr);
  gemm_bt<<<dim3(18, 98), 256, 0, stream>>>(hbuf, qkvw_b, qkv_b, nullptr,
                                            nullptr, qkv, nullptr, 3*EE, EE);
  hipFuncSetAttribute((const void*)attn_mfma,
                      hipFuncAttributeMaxDynamicSharedMemorySize, 163456);
  attn_mfma<<<BB*HH, 256, 163456, stream>>>(qkv, obuf);
  // out_pre = obuf @ wo^T + bo + emb (fp32 out) + fused LN2 stats
  gemm_bt<<<dim3(6, 98), 256, 0, stream>>>(obuf, wo_b, bo, emb_b,
                                           out, nullptr, stats + 128, EE, EE);
  ln_apply<<<BB*SE/4/256, 256, 0, stream>>>(out, nullptr, stats + 128, ln2w, ln2b,
                                            nullptr, out);
}

// Round 8
// 312.420 us; speedup vs baseline: 1.0947x; 1.0947x over previous
//
#include <hip/hip_runtime.h>
#include <hip/hip_bf16.h>

#define GRID14 14
#define SS 196
#define EE 768
#define HH 4
#define HD 192
#define BB 64
#define MM (BB*SS)       // 12544
#define SE (SS*EE)       // 150528

typedef __bf16 bf16x8 __attribute__((ext_vector_type(8)));
typedef __bf16 bf16x4 __attribute__((ext_vector_type(4)));
typedef float floatx4 __attribute__((ext_vector_type(4)));

__device__ __forceinline__ void glds16(const void* g, void* l) {
  __builtin_amdgcn_global_load_lds(
      (const __attribute__((address_space(1))) unsigned int*)g,
      (__attribute__((address_space(3))) unsigned int*)l, 16, 0, 0);
}

__device__ __forceinline__ unsigned short bfbits(float f) {
  __hip_bfloat16 h = __float2bfloat16(f);
  return *(unsigned short*)&h;
}

__device__ __forceinline__ float b2f(unsigned short u) {
  union { unsigned int i; float f; } x; x.i = (unsigned int)u << 16; return x.f;
}

// ---------------- patch extraction: x[64,3,224,224] f32 -> patches[12544,768] bf16
__global__ __launch_bounds__(256) void patch_kernel(const float* __restrict__ x,
                                                    __hip_bfloat16* __restrict__ p) {
  int idx = blockIdx.x * 256 + threadIdx.x;   // 8-elem group, total MM*96
  int k8 = idx % 96;
  int m  = idx / 96;
  int b = m / SS, s = m - b*SS;
  int gy = s / GRID14, gx = s - gy*GRID14;
  int k = k8 * 8;
  int c = k >> 8, py = (k >> 4) & 15, px = k & 15;
  const float* src = x + ((size_t)(b*3 + c)*224 + gy*16 + py)*224 + gx*16 + px;
  float4 f0 = *(const float4*)src;
  float4 f1 = *(const float4*)(src + 4);
  union { uint4 q; unsigned short u[8]; } t;
  t.u[0] = bfbits(f0.x); t.u[1] = bfbits(f0.y);
  t.u[2] = bfbits(f0.z); t.u[3] = bfbits(f0.w);
  t.u[4] = bfbits(f1.x); t.u[5] = bfbits(f1.y);
  t.u[6] = bfbits(f1.z); t.u[7] = bfbits(f1.w);
  *(uint4*)(p + (size_t)idx * 8) = t.q;
}

// ---------------- weight conversion + QKV weight/bias concat + stats zeroing
__global__ __launch_bounds__(256) void convert_weights(
    const float* __restrict__ cw, const float* __restrict__ wq,
    const float* __restrict__ wk, const float* __restrict__ wv,
    const float* __restrict__ wo, const float* __restrict__ bq,
    const float* __restrict__ bk, const float* __restrict__ bv,
    __hip_bfloat16* __restrict__ cw_b, __hip_bfloat16* __restrict__ qkvw_b,
    __hip_bfloat16* __restrict__ wo_b, float* __restrict__ qkv_bias,
    float* __restrict__ stats) {
  int i = blockIdx.x * 256 + threadIdx.x;
  const int WN = EE * EE;
  if (i < WN) {
    cw_b[i] = __float2bfloat16(cw[i]);
    wo_b[i] = __float2bfloat16(wo[i]);
    qkvw_b[i]        = __float2bfloat16(wq[i]);
    qkvw_b[WN + i]   = __float2bfloat16(wk[i]);
    qkvw_b[2*WN + i] = __float2bfloat16(wv[i]);
  }
  if (i < EE) { qkv_bias[i] = bq[i]; qkv_bias[EE+i] = bk[i]; qkv_bias[2*EE+i] = bv[i]; }
  if (i < 256) stats[i] = 0.f;
}

// ---------------- bf16 MFMA GEMM: out[M,N] = A[M,K] @ W[N,K]^T + bias (+skip)
// 128x128 tile, BK=64, global_load_lds width-16, XOR-swizzled LDS.
// outF: fp32 direct stores. outB: LDS-staged 16B/lane stores with optional
// coalesced bf16 skip-add. Optional fused LayerNorm stats in either path.
// NOTE: min-waves/EU = 3 (NOT 4): acc uses 64 AGPR; 4 waves/EU caps the
// unified file at 128/wave and spills (R7: VGPR 64, MfmaUtil 8%).
__global__ __launch_bounds__(256, 3) void gemm_bt(
    const __hip_bfloat16* __restrict__ A, const __hip_bfloat16* __restrict__ W,
    const float* __restrict__ bias, const __hip_bfloat16* __restrict__ skipB,
    float* __restrict__ outF, __hip_bfloat16* __restrict__ outB,
    float* __restrict__ stats, int N, int K) {
  __shared__ __align__(16) union SM {
    unsigned short ab[2][128*64];   // As, Bs (main loop)  32 KB
    unsigned short c[128*136];      // epilogue staging    34816 B
  } sm;
  __shared__ float red[16];
  const int tileM = blockIdx.y * 128;
  const int tileN = blockIdx.x * 128;
  const int tid  = threadIdx.x;
  const int lane = tid & 63;
  const int wave = tid >> 6;
  const int wrow = (wave >> 1) * 64;
  const int wcol = (wave & 1) * 64;
  const int lm = lane & 15;
  const int lq = lane >> 4;

  const int rt = tid >> 3;
  const int pc = tid & 7;
  const int sc = pc ^ (rt & 7);
  const __hip_bfloat16* aP = A + (size_t)(tileM + rt) * K + sc * 8;
  const __hip_bfloat16* bP = W + (size_t)(tileN + rt) * K + sc * 8;
  unsigned short* asl = sm.ab[0] + tid * 8;
  unsigned short* bsl = sm.ab[1] + tid * 8;
  const int f0 = lm & 7;

  floatx4 acc[4][4];
  #pragma unroll
  for (int i = 0; i < 4; ++i)
    #pragma unroll
    for (int j = 0; j < 4; ++j) acc[i][j] = (floatx4)0.0f;

  for (int k0 = 0; k0 < K; k0 += 64) {
    __syncthreads();
    #pragma unroll
    for (int i = 0; i < 4; ++i) glds16(aP + k0 + (size_t)(32*i)*K, asl + 2048*i);
    #pragma unroll
    for (int i = 0; i < 4; ++i) glds16(bP + k0 + (size_t)(32*i)*K, bsl + 2048*i);
    __syncthreads();
    #pragma unroll
    for (int h = 0; h < 2; ++h) {
      bf16x8 af[4], bfr[4];
      #pragma unroll
      for (int i = 0; i < 4; ++i)
        af[i]  = *(const bf16x8*)&sm.ab[0][(wrow + i*16 + lm)*64 + (((lq + 4*h) ^ f0))*8];
      #pragma unroll
      for (int j = 0; j < 4; ++j)
        bfr[j] = *(const bf16x8*)&sm.ab[1][(wcol + j*16 + lm)*64 + (((lq + 4*h) ^ f0))*8];
      #pragma unroll
      for (int i = 0; i < 4; ++i)
        #pragma unroll
        for (int j = 0; j < 4; ++j)
          acc[i][j] = __builtin_amdgcn_mfma_f32_16x16x32_bf16(af[i], bfr[j], acc[i][j], 0, 0, 0);
    }
  }

  const int rq = lq * 4;
  const int sA = tileM / SS;
  const int boundary = (sA + 1) * SS;
  float p0s = 0.f, p0q = 0.f, p1s = 0.f, p1q = 0.f;

  if (outF) {
    #pragma unroll
    for (int j = 0; j < 4; ++j) {
      int n = tileN + wcol + j*16 + lm;
      float bj = bias[n];
      #pragma unroll
      for (int i = 0; i < 4; ++i) {
        int mb = tileM + wrow + i*16 + rq;
        #pragma unroll
        for (int r = 0; r < 4; ++r) {
          int row = mb + r;
          size_t o = (size_t)row * N + n;
          float v = acc[i][j][r] + bj;
          if (skipB) v += __bfloat162float(skipB[o]);
          outF[o] = v;
          if (stats) {
            if (row < boundary) { p0s += v; p0q += v*v; }
            else                { p1s += v; p1q += v*v; }
          }
        }
      }
    }
  } else {
    // bf16 output: stage tile in LDS, then 16B/lane coalesced stores.
    // skip-add and stats happen in the coalesced store loop.
    __syncthreads();
    #pragma unroll
    for (int j = 0; j < 4; ++j) {
      int n = wcol + j*16 + lm;
      float bj = bias[tileN + n];
      #pragma unroll
      for (int i = 0; i < 4; ++i) {
        int rowb = wrow + i*16 + rq;
        #pragma unroll
        for (int r = 0; r < 4; ++r)
          sm.c[(rowb + r)*136 + n] = bfbits(acc[i][j][r] + bj);
      }
    }
    __syncthreads();
    #pragma unroll
    for (int f = tid; f < 2048; f += 256) {
      int row = f >> 4, ch = (f & 15) * 8;
      size_t o = (size_t)(tileM + row) * N + tileN + ch;
      uint4 val = *(const uint4*)&sm.c[row*136 + ch];
      if (skipB || stats) {
        unsigned short* vu = (unsigned short*)&val;
        float vs[8];
        if (skipB) {
          uint4 sk = *(const uint4*)(skipB + o);
          const unsigned short* su = (const unsigned short*)&sk;
          #pragma unroll
          for (int e = 0; e < 8; ++e) {
            float fv = b2f(vu[e]) + b2f(su[e]);
            vs[e] = fv;
            vu[e] = bfbits(fv);
          }
        } else {
          #pragma unroll
          for (int e = 0; e < 8; ++e) vs[e] = b2f(vu[e]);
        }
        if (stats) {
          float s = 0.f, q = 0.f;
          #pragma unroll
          for (int e = 0; e < 8; ++e) { s += vs[e]; q += vs[e]*vs[e]; }
          if (tileM + row < boundary) { p0s += s; p0q += q; }
          else                        { p1s += s; p1q += q; }
        }
      }
      *(uint4*)(outB + o) = val;
    }
  }

  if (stats) {
    #pragma unroll
    for (int off = 32; off; off >>= 1) {
      p0s += __shfl_down(p0s, off); p0q += __shfl_down(p0q, off);
      p1s += __shfl_down(p1s, off); p1q += __shfl_down(p1q, off);
    }
    if (lane == 0) {
      red[wave*4+0] = p0s; red[wave*4+1] = p0q;
      red[wave*4+2] = p1s; red[wave*4+3] = p1q;
    }
    __syncthreads();
    if (tid == 0) {
      atomicAdd(&stats[2*sA],   red[0]+red[4]+red[8]+red[12]);
      atomicAdd(&stats[2*sA+1], red[1]+red[5]+red[9]+red[13]);
      if (boundary <= tileM + 127 && sA + 1 < BB) {
        atomicAdd(&stats[2*sA+2], red[2]+red[6]+red[10]+red[14]);
        atomicAdd(&stats[2*sA+3], red[3]+red[7]+red[11]+red[15]);
      }
    }
  }
}

// ---------------- LN apply (stats = per-sample {sum, sumsq}); input fp32 OR bf16
__global__ __launch_bounds__(256) void ln_apply(const float* __restrict__ inF,
    const __hip_bfloat16* __restrict__ inB, const float* __restrict__ stats,
    const float* __restrict__ w, const float* __restrict__ bias,
    __hip_bfloat16* __restrict__ outB, float* __restrict__ outF) {
  int idx = blockIdx.x * 256 + threadIdx.x;      // float4 index, total 64*SE/4
  int samp = idx / (SE/4);
  int pos  = idx - samp * (SE/4);
  float S1 = stats[samp*2], S2 = stats[samp*2+1];
  float mu = S1 * (1.0f/SE);
  float var = S2 * (1.0f/SE) - mu*mu;
  float rstd = rsqrtf(var + 1e-5f);
  float4 v;
  if (inF) {
    v = ((const float4*)inF)[idx];
  } else {
    ushort4 u = ((const ushort4*)inB)[idx];
    v.x = b2f(u.x); v.y = b2f(u.y); v.z = b2f(u.z); v.w = b2f(u.w);
  }
  float4 w4 = ((const float4*)w)[pos];
  float4 b4 = ((const float4*)bias)[pos];
  float4 r;
  r.x = (v.x - mu)*rstd*w4.x + b4.x;
  r.y = (v.y - mu)*rstd*w4.y + b4.y;
  r.z = (v.z - mu)*rstd*w4.z + b4.z;
  r.w = (v.w - mu)*rstd*w4.w + b4.w;
  if (outF) {
    ((float4*)outF)[idx] = r;
  } else {
    ushort4 us;
    us.x = bfbits(r.x); us.y = bfbits(r.y);
    us.z = bfbits(r.z); us.w = bfbits(r.w);
    *(ushort4*)(outB + (size_t)idx * 4) = us;
  }
}

// ---------------- MFMA flash attention: one block per (b,h)
__device__ __forceinline__ int kv_byte(int row, int col) {
  int c8 = col >> 3;
  int swz = (c8 & 24) | ((c8 ^ row) & 7);
  return row*384 + swz*16 + (col & 7)*2;
}

__global__ __launch_bounds__(256) void attn_mfma(const __hip_bfloat16* __restrict__ qkv,
                                                 __hip_bfloat16* __restrict__ o) {
  extern __shared__ char smem[];
  unsigned short* Pb = (unsigned short*)(smem + 75264);   // stride 212 elems
  const int bh = blockIdx.x;
  const int b = bh >> 2, h = bh & 3;
  const int tid = threadIdx.x, lane = tid & 63, wave = tid >> 6;
  const int lm = lane & 15, lq = lane >> 4;

  {
    const __hip_bfloat16* kbase = qkv + (size_t)b*SS*2304 + EE + h*HD;
    for (int f = tid; f < 196*24; f += 256) {
      int row = f / 24, c8 = f % 24;
      uint4 v = *(const uint4*)(kbase + (size_t)row*2304 + c8*8);
      int swz = (c8 & 24) | ((c8 ^ row) & 7);
      *(uint4*)(smem + row*384 + swz*16) = v;
    }
  }
  __syncthreads();

  const float scale = 0.07216878364870323f;   // 1/sqrt(192)
  for (int qt = wave; qt < 13; qt += 4) {
    bf16x8 qf[6];
    const __hip_bfloat16* qrow = qkv + (size_t)(b*SS + qt*16 + lm)*2304 + h*HD + lq*8;
    #pragma unroll
    for (int c = 0; c < 6; ++c) qf[c] = *(const bf16x8*)(qrow + c*32);
    floatx4 acc[13];
    #pragma unroll
    for (int nt = 0; nt < 13; ++nt) acc[nt] = (floatx4)0.0f;
    #pragma unroll
    for (int nt = 0; nt < 13; ++nt) {
      int n = nt*16 + lm;
      #pragma unroll
      for (int c = 0; c < 6; ++c) {
        bf16x8 kf = *(const bf16x8*)(smem + kv_byte(n, c*32 + lq*8));
        acc[nt] = __builtin_amdgcn_mfma_f32_16x16x32_bf16(qf[c], kf, acc[nt], 0, 0, 0);
      }
    }
    float rmax[4] = {-1e30f, -1e30f, -1e30f, -1e30f};
    #pragma unroll
    for (int nt = 0; nt < 13; ++nt) {
      bool valid = (nt < 12) | (lm < 4);
      #pragma unroll
      for (int r = 0; r < 4; ++r) {
        float v = acc[nt][r] * scale;
        acc[nt][r] = v;
        if (valid) rmax[r] = fmaxf(rmax[r], v);
      }
    }
    #pragma unroll
    for (int x = 1; x < 16; x <<= 1)
      #pragma unroll
      for (int r = 0; r < 4; ++r) rmax[r] = fmaxf(rmax[r], __shfl_xor(rmax[r], x));
    float rsum[4] = {0.f, 0.f, 0.f, 0.f};
    #pragma unroll
    for (int nt = 0; nt < 13; ++nt) {
      bool valid = (nt < 12) | (lm < 4);
      #pragma unroll
      for (int r = 0; r < 4; ++r) {
        float e = valid ? __expf(acc[nt][r] - rmax[r]) : 0.f;
        acc[nt][r] = e;
        rsum[r] += e;
      }
    }
    #pragma unroll
    for (int x = 1; x < 16; x <<= 1)
      #pragma unroll
      for (int r = 0; r < 4; ++r) rsum[r] += __shfl_xor(rsum[r], x);
    float inv[4];
    #pragma unroll
    for (int r = 0; r < 4; ++r) inv[r] = 1.0f / rsum[r];
    #pragma unroll
    for (int nt = 0; nt < 13; ++nt) {
      int col = nt*16 + lm;
      #pragma unroll
      for (int r = 0; r < 4; ++r) {
        int row = qt*16 + lq*4 + r;
        if (row < SS) {
          Pb[row*212 + col] = bfbits(acc[nt][r] * inv[r]);
        }
      }
    }
  }
  __syncthreads();

  {
    const __hip_bfloat16* vbase = qkv + (size_t)b*SS*2304 + 2*EE + h*HD;
    for (int f = tid; f < 196*24; f += 256) {
      int row = f / 24, c8 = f % 24;
      uint4 v = *(const uint4*)(vbase + (size_t)row*2304 + c8*8);
      int swz = (c8 & 24) | ((c8 ^ row) & 7);
      *(uint4*)(smem + row*384 + swz*16) = v;
    }
  }
  __syncthreads();

  const int d0 = wave * 48;
  union U8 { bf16x8 v; unsigned short u[8]; };
  U8 vf[3][6]; U8 vtail[3];
  #pragma unroll
  for (int nn = 0; nn < 3; ++nn) {
    int d = d0 + nn*16 + lm;
    #pragma unroll
    for (int c = 0; c < 6; ++c) {
      int sb = c*32 + lq*8;
      #pragma unroll
      for (int j = 0; j < 8; ++j)
        vf[nn][c].u[j] = *(const unsigned short*)(smem + kv_byte(sb + j, d));
    }
    #pragma unroll
    for (int j = 0; j < 8; ++j) vtail[nn].u[j] = 0;
    if (lane < 16) {
      #pragma unroll
      for (int j = 0; j < 4; ++j)
        vtail[nn].u[j] = *(const unsigned short*)(smem + kv_byte(192 + j, d0 + nn*16 + lane));
    }
  }

  for (int qt = 0; qt < 13; ++qt) {
    floatx4 O[3];
    #pragma unroll
    for (int nn = 0; nn < 3; ++nn) O[nn] = (floatx4)0.0f;
    #pragma unroll
    for (int c = 0; c < 6; ++c) {
      int e0 = (qt*16 + lm)*212 + c*32 + lq*8;
      bf16x4 lo = *(const bf16x4*)(Pb + e0);
      bf16x4 hi = *(const bf16x4*)(Pb + e0 + 4);
      bf16x8 pf = __builtin_shufflevector(lo, hi, 0, 1, 2, 3, 4, 5, 6, 7);
      #pragma unroll
      for (int nn = 0; nn < 3; ++nn)
        O[nn] = __builtin_amdgcn_mfma_f32_16x16x32_bf16(pf, vf[nn][c].v, O[nn], 0, 0, 0);
    }
    {
      U8 pt;
      #pragma unroll
      for (int j = 0; j < 8; ++j) pt.u[j] = 0;
      if (lane < 16) {
        #pragma unroll
        for (int j = 0; j < 4; ++j) pt.u[j] = Pb[(qt*16 + lane)*212 + 192 + j];
      }
      #pragma unroll
      for (int nn = 0; nn < 3; ++nn)
        O[nn] = __builtin_amdgcn_mfma_f32_16x16x32_bf16(pt.v, vtail[nn].v, O[nn], 0, 0, 0);
    }
    #pragma unroll
    for (int nn = 0; nn < 3; ++nn) {
      #pragma unroll
      for (int r = 0; r < 4; ++r) {
        int q = qt*16 + lq*4 + r;
        if (q < SS)
          o[(size_t)(b*SS + q)*EE + h*HD + d0 + nn*16 + lm] = __float2bfloat16(O[nn][r]);
      }
    }
  }
}

extern "C" void kernel_launch(void* const* d_in, const int* in_sizes, int n_in,
                              void* d_out, int out_size, void* d_ws, size_t ws_size,
                              hipStream_t stream) {
  const float* x      = (const float*)d_in[0];
  const float* conv_w = (const float*)d_in[1];
  const float* conv_b = (const float*)d_in[2];
  const float* wq = (const float*)d_in[3];
  const float* bq = (const float*)d_in[4];
  const float* wk = (const float*)d_in[5];
  const float* bk = (const float*)d_in[6];
  const float* wv = (const float*)d_in[7];
  const float* bv = (const float*)d_in[8];
  const float* wo = (const float*)d_in[9];
  const float* bo = (const float*)d_in[10];
  const float* ln1w = (const float*)d_in[11];
  const float* ln1b = (const float*)d_in[12];
  const float* ln2w = (const float*)d_in[13];
  const float* ln2b = (const float*)d_in[14];
  float* out = (float*)d_out;

  char* ws = (char*)d_ws;
  __hip_bfloat16* patches = (__hip_bfloat16*)(ws);                // 19267584
  __hip_bfloat16* pre2    = (__hip_bfloat16*)(ws);                // reuse (patches dead after emb GEMM)
  __hip_bfloat16* cw_b    = (__hip_bfloat16*)(ws + 19267584);     //  1179648
  __hip_bfloat16* qkvw_b  = (__hip_bfloat16*)(ws + 20447232);     //  3538944
  __hip_bfloat16* wo_b    = (__hip_bfloat16*)(ws + 23986176);     //  1179648
  float*          qkv_b   = (float*)         (ws + 25165824);     //     9216
  __hip_bfloat16* emb_b   = (__hip_bfloat16*)(ws + 25175040);     // 19267584 (bf16)
  __hip_bfloat16* hbuf    = (__hip_bfloat16*)(ws + 63710208);     // 19267584
  __hip_bfloat16* qkv     = (__hip_bfloat16*)(ws + 82977792);     // 57802752
  __hip_bfloat16* obuf    = (__hip_bfloat16*)(ws + 140780544);    // 19267584
  float*          stats   = (float*)(ws + 160048128);             //     1024

  // stats[0..127] = LN1 {sum,sumsq} per sample; stats[128..255] = LN2
  convert_weights<<<2304, 256, 0, stream>>>(conv_w, wq, wk, wv, wo, bq, bk, bv,
                                            cw_b, qkvw_b, wo_b, qkv_b, stats);
  patch_kernel<<<MM*96/256, 256, 0, stream>>>(x, patches);
  // emb = patches @ conv_w^T + conv_b (bf16 out) + fused LN1 stats
  gemm_bt<<<dim3(6, 98), 256, 0, stream>>>(patches, cw_b, conv_b, nullptr,
                                           nullptr, emb_b, stats, EE, EE);
  ln_apply<<<BB*SE/4/256, 256, 0, stream>>>(nullptr, emb_b, stats, ln1w, ln1b,
                                            hbuf, nullptr);
  gemm_bt<<<dim3(18, 98), 256, 0, stream>>>(hbuf, qkvw_b, qkv_b, nullptr,
                                            nullptr, qkv, nullptr, 3*EE, EE);
  hipFuncSetAttribute((const void*)attn_mfma,
                      hipFuncAttributeMaxDynamicSharedMemorySize, 163456);
  attn_mfma<<<BB*HH, 256, 163456, stream>>>(qkv, obuf);
  // pre2 = obuf @ wo^T + bo + emb (bf16 out, coalesced skip-add) + fused LN2 stats
  gemm_bt<<<dim3(6, 98), 256, 0, stream>>>(obuf, wo_b, bo, emb_b,
                                           nullptr, pre2, stats + 128, EE, EE);
  ln_apply<<<BB*SE/4/256, 256, 0, stream>>>(nullptr, pre2, stats + 128, ln2w, ln2b,
                                            nullptr, out);
}